// Round 1
// 1324.194 us; speedup vs baseline: 1.0108x; 1.0108x over previous
//
#include <hip/hip_runtime.h>

// Layout of d_out (all f32): [nids M][means M*128][last_ts M]
// Layout of d_ws: [seg_start M ints][seg_end M ints]

__global__ void init_kernel(const int* __restrict__ nids, float* __restrict__ out_nids,
                            int* __restrict__ seg_start, int* __restrict__ seg_end, int M) {
    int i = blockIdx.x * blockDim.x + threadIdx.x;
    if (i < M) {
        out_nids[i]  = (float)nids[i];
        seg_start[i] = 0;
        seg_end[i]   = 0;  // start==end -> empty segment
    }
}

__global__ void bounds_kernel(const int* __restrict__ seg,
                              int* __restrict__ seg_start, int* __restrict__ seg_end, int N) {
    int i = blockIdx.x * blockDim.x + threadIdx.x;
    if (i >= N) return;
    int s = seg[i];
    if (i == 0     || seg[i - 1] != s) seg_start[s] = i;
    if (i == N - 1 || seg[i + 1] != s) seg_end[s]   = i + 1;  // exclusive
}

// One wave (64 lanes) per segment.
// float4 lanes: lanes 0-31 cover row r (128 floats), lanes 32-63 cover row r+1.
// -> 1 KB contiguous per load instruction, 2 rows/iteration, 2x unrolled (2 KB in flight/wave).
__global__ __launch_bounds__(256) void mean_kernel(
        const float* __restrict__ msgs, const float* __restrict__ ts,
        const int* __restrict__ seg_start, const int* __restrict__ seg_end,
        float* __restrict__ out_msgs, float* __restrict__ out_ts, int M) {
    int gtid = blockIdx.x * blockDim.x + threadIdx.x;
    int wave = gtid >> 6;          // wave64, one segment per wave
    int lane = threadIdx.x & 63;
    if (wave >= M) return;

    int s   = seg_start[wave];
    int e   = seg_end[wave];
    int cnt = e - s;

    int h = lane >> 5;   // which row of the current row-pair this lane reads
    int c = lane & 31;   // float4 column (4c .. 4c+3)

    float ax = 0.f, ay = 0.f, az = 0.f, aw = 0.f;

    // row stride = 32 float4; pair stride = 64 float4
    const float4* p = (const float4*)msgs + ((size_t)(s + h)) * 32 + c;
    int iters = cnt >> 1;   // row-pairs
    int r = 0;
    for (; r + 2 <= iters; r += 2) {
        float4 v0 = p[(size_t)r * 64];
        float4 v1 = p[(size_t)r * 64 + 64];
        ax += v0.x; ay += v0.y; az += v0.z; aw += v0.w;
        ax += v1.x; ay += v1.y; az += v1.z; aw += v1.w;
    }
    if (r < iters) {
        float4 v = p[(size_t)r * 64];
        ax += v.x; ay += v.y; az += v.z; aw += v.w;
    }
    if ((cnt & 1) && h == 0) {
        // odd count: last row e-1 handled by the low half-wave
        float4 v = ((const float4*)msgs)[((size_t)(e - 1)) * 32 + c];
        ax += v.x; ay += v.y; az += v.z; aw += v.w;
    }

    // combine the two halves: lane l <-> lane l^32
    ax += __shfl_xor(ax, 32);
    ay += __shfl_xor(ay, 32);
    az += __shfl_xor(az, 32);
    aw += __shfl_xor(aw, 32);

    float inv = (cnt > 0) ? (1.0f / (float)cnt) : 0.0f;
    if (h == 0) {
        float4 o = make_float4(ax * inv, ay * inv, az * inv, aw * inv);
        ((float4*)out_msgs)[(size_t)wave * 32 + c] = o;  // 32 lanes x 16 B = full 128-float row
    }

    if (lane == 0) {
        // last_idx = max pos in segment -> e-1; empty segment clips to index 0
        out_ts[wave] = (cnt > 0) ? ts[e - 1] : ts[0];
    }
}

extern "C" void kernel_launch(void* const* d_in, const int* in_sizes, int n_in,
                              void* d_out, int out_size, void* d_ws, size_t ws_size,
                              hipStream_t stream) {
    const int*   nids = (const int*)  d_in[0];   // [M] int32
    const float* msgs = (const float*)d_in[1];   // [N*128] f32
    const float* ts   = (const float*)d_in[2];   // [N] f32
    const int*   seg  = (const int*)  d_in[3];   // [N] int32, sorted
    // d_in[4] = num_segments scalar; M from in_sizes[0]

    const int M = in_sizes[0];
    const int N = in_sizes[2];

    float* out_nids = (float*)d_out;
    float* out_msgs = out_nids + M;
    float* out_ts   = out_msgs + (size_t)M * 128;

    int* seg_start = (int*)d_ws;
    int* seg_end   = seg_start + M;

    init_kernel  <<<(M + 255) / 256, 256, 0, stream>>>(nids, out_nids, seg_start, seg_end, M);
    bounds_kernel<<<(N + 255) / 256, 256, 0, stream>>>(seg, seg_start, seg_end, N);
    // 4 waves per 256-thread block, one wave per segment
    mean_kernel  <<<(M + 3) / 4, 256, 0, stream>>>(msgs, ts, seg_start, seg_end, out_msgs, out_ts, M);
}